// Round 5
// baseline (138.244 us; speedup 1.0000x reference)
//
#include <hip/hip_runtime.h>
#include <stdint.h>

// Problem shape (fixed by setup_inputs): B=16, C=64, H=128, W=128, fp32 throughout
#define CCH   64
#define HWSZ  16384             // H*W = 2^14
#define BATCH 16
#define NSLAB (BATCH * CCH)     // 1024 contiguous (b,c) slabs of 16384 floats
#define NPC   (BATCH * HWSZ)    // elements per channel = 262144
#define TPB   512               // threads per block (8 waves)
#define VPT   8                 // float4 held per thread: 8*512*4 = 16384 floats/slab

static constexpr float COS_RY = 0.99500416527802576610f; // cos(0.1)
static constexpr float EPS    = 1e-6f;
#define SENTINEL 0xFFFFFFFFu    // NaN bit pattern; finite partial sums never equal it

typedef float fvec4 __attribute__((ext_vector_type(4)));

__device__ __forceinline__ float qpix(float x) {
    // z = cos(0.1)*cos(x); q = z + z^2 + z^3 + z^4
    float z = COS_RY * __cosf(x);
    return z * (1.0f + z * (1.0f + z * (1.0f + z)));
}

// Reset all 2048 partial-sum slots to SENTINEL. Agent-scope atomic stores land at
// the coherence point, where the fused kernel's pollers read.
__global__ void init_kernel(uint32_t* __restrict__ slots) {
    const int t = threadIdx.x;
    #pragma unroll
    for (int i = 0; i < 8; ++i)
        __hip_atomic_store(&slots[i * 256 + t], SENTINEL, __ATOMIC_RELAXED,
                           __HIP_MEMORY_SCOPE_AGENT);
}

// Single fused pass, one 512-thread block per (b,c) slab. Each thread loads
// 8 float4 (32 VGPRs of data) and HOLDS them across a fence-free per-channel
// sentinel sync, so x is read from HBM exactly once and out written once:
// 128 MiB total = the op's HBM floor. Round-1's version of this spilled
// (16 float4 held, demand ~80 regs vs the allocator's 64); halving per-thread
// state to 32 data regs + ~20 temps fits the 64-reg budget.
//
// Deadlock safety for the spin: grid = 1024 blocks x 512 thr = 4 blocks/CU =
// exactly the 2048-thread/CU capacity -> full co-residency on 256 CUs.
// amdgpu_waves_per_eu(8) makes 8 waves/EU (= 4 blocks/CU) a HARD floor: the
// allocator must fit VGPR<=64, spilling rather than dropping occupancy, so
// worst case is slow, never deadlocked. LDS ~72 B. Sync is relaxed agent
// atomics only (data == ready flag) -> no buffer_inv/wbl2 storm (round-1 bug).
__global__ __launch_bounds__(TPB)
__attribute__((amdgpu_waves_per_eu(8)))
void fused_kernel(const float* __restrict__ x,
                  const float* __restrict__ gamma,
                  const float* __restrict__ beta,
                  uint32_t* __restrict__ slots,
                  float* __restrict__ out) {
    const int slab = blockIdx.x;          // b*CCH + c
    const int c    = slab & (CCH - 1);
    const int b    = slab >> 6;
    const int tid  = threadIdx.x;

    // ---- load the slab once; keep it in registers (32 VGPRs) ----
    const fvec4* __restrict__ p = (const fvec4*)(x + (size_t)slab * HWSZ);
    fvec4 v[VPT];
    #pragma unroll
    for (int i = 0; i < VPT; ++i)
        v[i] = p[i * TPB + tid];

    // ---- phase A: moments from the held registers ----
    float s = 0.0f, s2 = 0.0f;
    #pragma unroll
    for (int i = 0; i < VPT; ++i) {
        const float q0 = qpix(v[i].x), q1 = qpix(v[i].y);
        const float q2 = qpix(v[i].z), q3 = qpix(v[i].w);
        s  += (q0 + q1) + (q2 + q3);
        s2 += (q0 * q0 + q1 * q1) + (q2 * q2 + q3 * q3);
    }
    #pragma unroll
    for (int off = 32; off > 0; off >>= 1) {
        s  += __shfl_down(s,  off, 64);
        s2 += __shfl_down(s2, off, 64);
    }

    __shared__ float ls[8], ls2[8], sh[2];
    const int wave = tid >> 6, lane = tid & 63;
    if (lane == 0) { ls[wave] = s; ls2[wave] = s2; }
    __syncthreads();

    // ---- publish this block's partial pair (relaxed, to the coherence point) ----
    if (tid == 0) {
        float bs = 0.0f, bs2 = 0.0f;
        #pragma unroll
        for (int w = 0; w < 8; ++w) { bs += ls[w]; bs2 += ls2[w]; }
        uint32_t u  = __float_as_uint(bs);
        uint32_t u2 = __float_as_uint(bs2);
        if (u  == SENTINEL) u  ^= 1u;    // finite sums can't be the NaN sentinel,
        if (u2 == SENTINEL) u2 ^= 1u;    // but guard anyway
        const int idx = c * BATCH + b;
        __hip_atomic_store(&slots[idx], u, __ATOMIC_RELAXED,
                           __HIP_MEMORY_SCOPE_AGENT);
        __hip_atomic_store(&slots[NSLAB + idx], u2, __ATOMIC_RELAXED,
                           __HIP_MEMORY_SCOPE_AGENT);
    }

    // ---- lanes 0..15 poll the channel's 16 partial pairs (data == flag) ----
    if (tid < BATCH) {
        const int base = c * BATCH + tid;
        uint32_t u, u2;
        for (;;) {
            u  = __hip_atomic_load(&slots[base], __ATOMIC_RELAXED,
                                   __HIP_MEMORY_SCOPE_AGENT);
            u2 = __hip_atomic_load(&slots[NSLAB + base], __ATOMIC_RELAXED,
                                   __HIP_MEMORY_SCOPE_AGENT);
            if (u != SENTINEL && u2 != SENTINEL) break;
            __builtin_amdgcn_s_sleep(4);
        }
        float a  = __uint_as_float(u);
        float a2 = __uint_as_float(u2);
        #pragma unroll
        for (int off = 8; off > 0; off >>= 1) {
            a  += __shfl_down(a,  off, 16);
            a2 += __shfl_down(a2, off, 16);
        }
        if (tid == 0) {
            const float invn = 1.0f / (float)NPC;
            const float mean = a * invn;
            const float var  = a2 * invn - mean * mean;
            const float inv  = rsqrtf(var + EPS);
            const float sc   = gamma[c] * inv;
            sh[0] = sc;
            sh[1] = beta[c] - mean * sc;
        }
    }
    __syncthreads();   // other waves park here while wave 0 polls
    const float scale = sh[0], shift = sh[1];

    // ---- phase B: recompute q from register-held x, normalize, residual ----
    fvec4* __restrict__ po = (fvec4*)(out + (size_t)slab * HWSZ);
    #pragma unroll
    for (int i = 0; i < VPT; ++i) {
        fvec4 o;
        o.x = fmaxf(qpix(v[i].x) * scale + shift, 0.0f) + v[i].x;
        o.y = fmaxf(qpix(v[i].y) * scale + shift, 0.0f) + v[i].y;
        o.z = fmaxf(qpix(v[i].z) * scale + shift, 0.0f) + v[i].z;
        o.w = fmaxf(qpix(v[i].w) * scale + shift, 0.0f) + v[i].w;
        __builtin_nontemporal_store(o, &po[i * TPB + tid]);
    }
}

extern "C" void kernel_launch(void* const* d_in, const int* in_sizes, int n_in,
                              void* d_out, int out_size, void* d_ws, size_t ws_size,
                              hipStream_t stream) {
    const float* x     = (const float*)d_in[0];
    const float* gamma = (const float*)d_in[1];
    const float* beta  = (const float*)d_in[2];
    uint32_t* slots = (uint32_t*)d_ws;   // 2048 u32: [0,1024) sums, [1024,2048) sumsq

    init_kernel<<<1, 256, 0, stream>>>(slots);
    fused_kernel<<<NSLAB, TPB, 0, stream>>>(x, gamma, beta, slots, (float*)d_out);
}

// Round 6
// 118.256 us; speedup vs baseline: 1.1690x; 1.1690x over previous
//
#include <hip/hip_runtime.h>
#include <stdint.h>

// Problem shape (fixed by setup_inputs): B=16, C=64, H=128, W=128, fp32 throughout
#define CCH   64
#define HWSZ  16384            // H*W = 2^14
#define BATCH 16
#define NSLAB (BATCH * CCH)    // 1024 contiguous (b,c) slabs of 16384 floats
#define SEGS  4                // stats segments per slab
#define NSEG  (NSLAB * SEGS)   // 4096 stats blocks / partials per moment
#define NPC   (BATCH * HWSZ)   // elements per channel = 262144
#define NTOT  (BATCH * CCH * HWSZ)

static constexpr float COS_RY = 0.99500416527802576610f; // cos(0.1)
static constexpr float EPS    = 1e-6f;

typedef float fvec4 __attribute__((ext_vector_type(4)));  // native vector for nt-store

__device__ __forceinline__ float qpix(float x) {
    // z = cos(0.1)*cos(x); q = z + z^2 + z^3 + z^4
    float z = COS_RY * __cosf(x);
    return z * (1.0f + z * (1.0f + z * (1.0f + z)));
}

// Pass 1: per-(channel,segment) partial sums, plain stores (no memset, no atomics).
// Block blk: slab = blk>>2 (= b*CCH+c), seg = blk&3. Each block covers 4096 floats.
// Partial layout: ps[c*64 + b*4 + seg] so each channel's 64 partials are contiguous.
__global__ __launch_bounds__(256) void stats_kernel(
        const float* __restrict__ x, float* __restrict__ ps) {
    const int blk  = blockIdx.x;          // 0..4095
    const int slab = blk >> 2;            // b*CCH + c
    const int seg  = blk & (SEGS - 1);
    const int c    = slab & (CCH - 1);
    const int b    = slab >> 6;
    const float4* __restrict__ p =
        (const float4*)(x + (size_t)slab * HWSZ + (size_t)seg * 4096);

    float s = 0.0f, s2 = 0.0f;
    #pragma unroll
    for (int it = 0; it < 4; ++it) {      // 4096 / (256*4) = 4
        const float4 v = p[it * 256 + (int)threadIdx.x];
        const float q0 = qpix(v.x), q1 = qpix(v.y);
        const float q2 = qpix(v.z), q3 = qpix(v.w);
        s  += (q0 + q1) + (q2 + q3);
        s2 += (q0 * q0 + q1 * q1) + (q2 * q2 + q3 * q3);
    }
    #pragma unroll
    for (int off = 32; off > 0; off >>= 1) {
        s  += __shfl_down(s,  off, 64);
        s2 += __shfl_down(s2, off, 64);
    }
    __shared__ float ls[4], ls2[4];
    const int wave = threadIdx.x >> 6, lane = threadIdx.x & 63;
    if (lane == 0) { ls[wave] = s; ls2[wave] = s2; }
    __syncthreads();
    if (threadIdx.x == 0) {
        const int idx = c * 64 + b * SEGS + seg;
        ps[idx]        = (ls[0]  + ls[1])  + (ls[2]  + ls[3]);
        ps[NSEG + idx] = (ls2[0] + ls2[1]) + (ls2[2] + ls2[3]);
    }
}

// Pass 2: block = 2048-float channel-uniform tile (8 per slab).
// First wave reduces the channel's 64 partials; all threads then apply
// y = relu((q-mean)*rsqrt(var+eps)*gamma+beta) + x with nontemporal stores.
__global__ __launch_bounds__(256) void apply_kernel(
        const float* __restrict__ x,
        const float* __restrict__ gamma,
        const float* __restrict__ beta,
        const float* __restrict__ ps,
        float* __restrict__ out) {
    const size_t blockBase = (size_t)blockIdx.x * 2048;   // floats
    const int c = (int)((blockBase >> 14) & (CCH - 1));   // uniform per block
    const int tid = threadIdx.x;

    // issue main loads early (independent of the reduction)
    const float4* __restrict__ p = (const float4*)(x + blockBase);
    const float4 v0 = p[tid];
    const float4 v1 = p[256 + tid];

    __shared__ float sh[2];
    if (tid < 64) {
        float a  = ps[c * 64 + tid];
        float a2 = ps[NSEG + c * 64 + tid];
        #pragma unroll
        for (int off = 32; off > 0; off >>= 1) {
            a  += __shfl_down(a,  off, 64);
            a2 += __shfl_down(a2, off, 64);
        }
        if (tid == 0) {
            const float invn = 1.0f / (float)NPC;
            const float mean = a * invn;
            const float var  = a2 * invn - mean * mean;
            const float inv  = rsqrtf(var + EPS);
            const float sc   = gamma[c] * inv;
            sh[0] = sc;
            sh[1] = beta[c] - mean * sc;
        }
    }
    __syncthreads();
    const float scale = sh[0], shift = sh[1];

    fvec4 o0, o1;
    o0.x = fmaxf(qpix(v0.x) * scale + shift, 0.0f) + v0.x;
    o0.y = fmaxf(qpix(v0.y) * scale + shift, 0.0f) + v0.y;
    o0.z = fmaxf(qpix(v0.z) * scale + shift, 0.0f) + v0.z;
    o0.w = fmaxf(qpix(v0.w) * scale + shift, 0.0f) + v0.w;
    o1.x = fmaxf(qpix(v1.x) * scale + shift, 0.0f) + v1.x;
    o1.y = fmaxf(qpix(v1.y) * scale + shift, 0.0f) + v1.y;
    o1.z = fmaxf(qpix(v1.z) * scale + shift, 0.0f) + v1.z;
    o1.w = fmaxf(qpix(v1.w) * scale + shift, 0.0f) + v1.w;

    fvec4* __restrict__ po = (fvec4*)(out + blockBase);
    __builtin_nontemporal_store(o0, &po[tid]);
    __builtin_nontemporal_store(o1, &po[256 + tid]);
}

extern "C" void kernel_launch(void* const* d_in, const int* in_sizes, int n_in,
                              void* d_out, int out_size, void* d_ws, size_t ws_size,
                              hipStream_t stream) {
    const float* x     = (const float*)d_in[0];
    const float* gamma = (const float*)d_in[1];
    const float* beta  = (const float*)d_in[2];
    float* out = (float*)d_out;
    float* ps  = (float*)d_ws;   // 2*NSEG floats = 32 KB, fully overwritten by stats

    stats_kernel<<<NSEG, 256, 0, stream>>>(x, ps);

    const int apply_blocks = NTOT / 2048;   // 8192
    apply_kernel<<<apply_blocks, 256, 0, stream>>>(x, gamma, beta, ps, out);
}